// Round 8
// baseline (906.430 us; speedup 1.0000x reference)
//
#include <hip/hip_runtime.h>

// MANNet forward, MI355X gfx950. Inputs fp32 (+int32 ids), output fp32.
// R8: k_gru gh via ds_write_b64 col-major; flush folds hi/lo+agg (k_hilo gone);
// softmax inlined into k_wsum; cmb merged into k_score. 10 dispatches.

#define DEV static __device__ __forceinline__
#define BAR_LGKM() __asm__ volatile("s_waitcnt lgkmcnt(0)\ns_barrier" ::: "memory")

typedef __attribute__((ext_vector_type(4))) float f32x4;
typedef __attribute__((ext_vector_type(8))) short s16x8;
typedef __attribute__((ext_vector_type(4))) unsigned int u32x4;

constexpr int T = 256, E = 300, EP = 320, H = 128, H2 = 256, H3 = 384, H12 = 1536;
constexpr int M = 1024;            // B*T
constexpr int STY = 262144;        // 4*T*T elements per score type

DEV float b2f(unsigned short h) { return __uint_as_float(((unsigned)h) << 16); }
DEV unsigned short f2b(float f) {
  unsigned u = __float_as_uint(f);
  u += 0x7fff + ((u >> 16) & 1);            // RNE
  return (unsigned short)(u >> 16);
}
DEV float sigm(float x) { return 1.f / (1.f + __expf(-x)); }
DEV float tanh_f(float x) { float e = __expf(2.f * x); return 1.f - 2.f / (e + 1.f); }

DEV s16x8 ldfrag(const unsigned short* p) {
  u32x4 v = *(const u32x4*)p;
  return __builtin_bit_cast(s16x8, v);
}
DEV f32x4 mfma16(s16x8 a, s16x8 b, f32x4 c) {
  return __builtin_amdgcn_mfma_f32_16x16x32_bf16(a, b, c, 0, 0, 0);
}

// ---------------- fused staging: 9x cvt + embed + padw ----------------

struct StageArgs {
  const float* cs[9]; unsigned short* cd[9]; int cn[9];
  const int* idx; const float* emb; unsigned short* xhi; unsigned short* xlo;
  const float* lW; const float* rW; unsigned short* wpad;
};

__global__ void k_stage(StageArgs sa) {
  int seg = blockIdx.y;
  int i = blockIdx.x * 256 + threadIdx.x;
  if (seg < 9) {
    if (i < sa.cn[seg]) sa.cd[seg][i] = f2b(sa.cs[seg][i]);
    return;
  }
  if (seg == 9) {
    if (i >= M * EP) return;
    int m = i / EP, e = i - m * EP;
    int r = sa.idx[m];
    float v = (e < E) ? sa.emb[(size_t)r * E + e] : 0.f;
    unsigned short hi = f2b(v);
    sa.xhi[i] = hi;
    sa.xlo[i] = f2b(v - b2f(hi));
    return;
  }
  if (i >= 4 * H3 * EP) return;
  int e = i % EP, n = (i / EP) % H3, uu = i / (EP * H3);
  const float* src = (uu < 2 ? sa.lW : sa.rW) + (size_t)((uu & 1) * H3 + n) * E;
  sa.wpad[i] = (e < E) ? f2b(src[e]) : (unsigned short)0;
}

// ---------------- generic GEMM: C = (Ahi+Alo) @ W^T (+bias), fp32 out ----------

struct GemmDesc {
  const unsigned short* Ahi; const unsigned short* Alo; const unsigned short* W;
  const float* bias; float* Cf; int N; int K;
};
struct GemmBatch { GemmDesc d[8]; };

__global__ __launch_bounds__(256) void k_gemm(GemmBatch gb) {
  GemmDesc g = gb.d[blockIdx.z];
  int nb = blockIdx.y * 64;
  if (nb >= g.N) return;
  int mb = blockIdx.x * 64;
  int lane = threadIdx.x & 63, w = threadIdx.x >> 6, quad = lane >> 4, l16 = lane & 15;
  int K = g.K;
  const unsigned short* Ahp = g.Ahi + (size_t)(mb + w * 16 + l16) * K + quad * 8;
  const unsigned short* Alp = g.Alo + (size_t)(mb + w * 16 + l16) * K + quad * 8;
  const unsigned short* Wp = g.W + (size_t)(nb + l16) * K + quad * 8;
  f32x4 acc[4];
  #pragma unroll
  for (int nt = 0; nt < 4; ++nt) acc[nt] = f32x4{0.f, 0.f, 0.f, 0.f};
  for (int k = 0; k < K; k += 32) {
    s16x8 ah = ldfrag(Ahp + k);
    s16x8 al = ldfrag(Alp + k);
    #pragma unroll
    for (int nt = 0; nt < 4; ++nt) {
      s16x8 b = ldfrag(Wp + (size_t)nt * 16 * K + k);
      acc[nt] = mfma16(ah, b, acc[nt]);
      acc[nt] = mfma16(al, b, acc[nt]);
    }
  }
  int mr0 = mb + w * 16 + quad * 4;
  #pragma unroll
  for (int nt = 0; nt < 4; ++nt) {
    int col = nb + nt * 16 + l16;
    float bv = g.bias ? g.bias[col] : 0.f;
    #pragma unroll
    for (int r = 0; r < 4; ++r)
      g.Cf[(size_t)(mr0 + r) * g.N + col] = acc[nt][r] + bv;
  }
}

// ---------------- GRU recurrence ----------------
// gh2 col-major: gh2[(w*96 + gcol)*10 + row], rows 0-3 hi-batches, 4-7 lo.
// Flush (every 4 steps) writes outf fp32 + hi/lo bf16 (+ optional agg copy).

struct RecArgs {
  const unsigned short* whh[4];
  const float* pre[4];
  float* outf[4];
  unsigned short* outhi[4];
  unsigned short* outlo[4];
  unsigned short* agghi[4];      // null -> no agg copy
  unsigned short* agglo[4];
  const float* bhh[4];
  int colOff[4];
  int dir[4];
};

__global__ __launch_bounds__(256) void k_gru(RecArgs ra) {
  int u = blockIdx.x;
  __shared__ __align__(16) unsigned short hs[2][16 * 136];
  __shared__ __align__(16) float gh2[4 * 96 * 10];
  int tid = threadIdx.x, lane = tid & 63, w = tid >> 6;
  int quad = lane >> 4, l16 = lane & 15;
  for (int i = tid; i < 2 * 16 * 136; i += 256) ((unsigned short*)hs)[i] = 0;
  const unsigned short* whh = ra.whh[u];
  s16x8 bq[6][4];
  #pragma unroll
  for (int nt = 0; nt < 6; ++nt) {
    int row = (nt >> 1) * 128 + w * 32 + (nt & 1) * 16 + l16;
    #pragma unroll
    for (int kc = 0; kc < 4; ++kc)
      bq[nt][kc] = ldfrag(whh + (size_t)row * H + kc * 32 + quad * 8);
  }
  const float* bhh = ra.bhh[u];
  const float* pre = ra.pre[u];
  float* outf = ra.outf[u];
  unsigned short* outhi = ra.outhi[u];
  unsigned short* outlo = ra.outlo[u];
  unsigned short* agghi = ra.agghi[u];
  unsigned short* agglo = ra.agglo[u];
  int colOff = ra.colOff[u], dir = ra.dir[u];
  int dd = lane & 31, bp = lane >> 5, b2 = bp + 2;
  int d = w * 32 + dd;
  float bh_r = bhh[d], bh_z = bhh[d + 128], bh_n = bhh[d + 256];
  float hf0 = 0.f, hf1 = 0.f;
  float ob0[4], ob1[4];
  int t0 = dir ? (T - 1) : 0;
  {
    const float* q0 = pre + (size_t)(bp * T + t0) * H3 + d;
    const float* q1 = pre + (size_t)(b2 * T + t0) * H3 + d;
    ob0[0] = q0[0]; ob0[1] = q0[128]; ob0[2] = q0[256];
    ob1[0] = q1[0]; ob1[1] = q1[128]; ob1[2] = q1[256];
  }
  float n_pr0 = ob0[0], n_pz0 = ob0[1], n_pn0 = ob0[2];
  float n_pr1 = ob1[0], n_pz1 = ob1[1], n_pn1 = ob1[2];
  __syncthreads();
  for (int sb = 0; sb < T; sb += 4) {
    #pragma unroll
    for (int ss = 0; ss < 4; ++ss) {
      int s = sb + ss;
      float pr0 = n_pr0, pz0 = n_pz0, pn0 = n_pn0;
      float pr1 = n_pr1, pz1 = n_pz1, pn1 = n_pn1;
      int sn = (s + 1 < T) ? (s + 1) : s;
      int tn = dir ? (T - 1 - sn) : sn;
      const float* f0 = pre + (size_t)(bp * T + tn) * H3 + d;
      const float* f1 = pre + (size_t)(b2 * T + tn) * H3 + d;
      n_pr0 = f0[0]; n_pz0 = f0[128]; n_pn0 = f0[256];
      n_pr1 = f1[0]; n_pz1 = f1[128]; n_pn1 = f1[256];
      const unsigned short* hcur = hs[ss & 1];
      unsigned short* hnxt = hs[(ss & 1) ^ 1];
      s16x8 ah[4];
      #pragma unroll
      for (int kc = 0; kc < 4; ++kc)
        ah[kc] = ldfrag(hcur + l16 * 136 + kc * 32 + quad * 8);
      f32x4 acc[6];
      #pragma unroll
      for (int nt = 0; nt < 6; ++nt) acc[nt] = f32x4{0.f, 0.f, 0.f, 0.f};
      #pragma unroll
      for (int kc = 0; kc < 4; ++kc) {
        #pragma unroll
        for (int nt = 0; nt < 6; ++nt)
          acc[nt] = mfma16(ah[kc], bq[nt][kc], acc[nt]);
      }
      if (quad < 2) {                         // rows quad*4..+3 (hi / lo)
        #pragma unroll
        for (int nt = 0; nt < 6; ++nt) {
          int gcol = (nt >> 1) * 32 + (nt & 1) * 16 + l16;
          float2* p = (float2*)(gh2 + ((size_t)(w * 96 + gcol)) * 10 + quad * 4);
          p[0] = float2{acc[nt][0], acc[nt][1]};
          p[1] = float2{acc[nt][2], acc[nt][3]};
        }
      }
      __asm__ volatile("s_waitcnt lgkmcnt(0)" ::: "memory");
      const float* g0 = gh2 + ((size_t)(w * 96 + dd)) * 10;
      const float* g1 = gh2 + ((size_t)(w * 96 + 32 + dd)) * 10;
      const float* g2 = gh2 + ((size_t)(w * 96 + 64 + dd)) * 10;
      float r0 = g0[bp] + g0[4 + bp];
      float z0 = g1[bp] + g1[4 + bp];
      float nv0 = g2[bp] + g2[4 + bp];
      float r1 = g0[b2] + g0[4 + b2];
      float z1 = g1[b2] + g1[4 + b2];
      float nv1 = g2[b2] + g2[4 + b2];
      float rg0 = sigm(pr0 + r0 + bh_r);
      float zg0 = sigm(pz0 + z0 + bh_z);
      float ng0 = tanh_f(pn0 + rg0 * (nv0 + bh_n));
      hf0 = (1.f - zg0) * ng0 + zg0 * hf0;
      unsigned short hi0 = f2b(hf0);
      hnxt[bp * 136 + d] = hi0;
      hnxt[(4 + bp) * 136 + d] = f2b(hf0 - b2f(hi0));
      ob0[ss] = hf0;
      float rg1 = sigm(pr1 + r1 + bh_r);
      float zg1 = sigm(pz1 + z1 + bh_z);
      float ng1 = tanh_f(pn1 + rg1 * (nv1 + bh_n));
      hf1 = (1.f - zg1) * ng1 + zg1 * hf1;
      unsigned short hi1 = f2b(hf1);
      hnxt[b2 * 136 + d] = hi1;
      hnxt[(4 + b2) * 136 + d] = f2b(hf1 - b2f(hi1));
      ob1[ss] = hf1;
      BAR_LGKM();                             // no vmcnt drain
    }
    #pragma unroll
    for (int qq = 0; qq < 4; ++qq) {
      int sq = sb + qq;
      int tq = dir ? (T - 1 - sq) : sq;
      float v0 = ob0[qq], v1 = ob1[qq];
      unsigned short h0 = f2b(v0), h1 = f2b(v1);
      unsigned short l0 = f2b(v0 - b2f(h0)), l1 = f2b(v1 - b2f(h1));
      size_t o0 = (size_t)(bp * T + tq) * H2 + colOff + d;
      size_t o1 = (size_t)(b2 * T + tq) * H2 + colOff + d;
      outf[o0] = v0; outhi[o0] = h0; outlo[o0] = l0;
      outf[o1] = v1; outhi[o1] = h1; outlo[o1] = l1;
      if (agghi) {
        size_t a0 = (size_t)(bp * T + tq) * H12 + colOff + d;
        size_t a1 = (size_t)(b2 * T + tq) * H12 + colOff + d;
        agghi[a0] = h0; agglo[a0] = l0;
        agghi[a1] = h1; agglo[a1] = l1;
      }
    }
  }
}

// ---------------- scores (merged): y=0,1 -> ds; y=2 -> cmb ----------------

struct ScArgs {
  const unsigned short* Xhi[2];
  const float* Rf; const float* Wt[2]; const float* vt[2]; float* So[2];
  const float *Hc, *Rc, *Hm, *Rm, *HB, *hrf, *vcf, *vmf; float* S;
};

__global__ __launch_bounds__(256, 2) void k_score(ScArgs a) {
  __shared__ __align__(16) unsigned char smem[65536];
  int which = blockIdx.y;
  int bi = blockIdx.x, b = bi >> 8;
  int tid = threadIdx.x;
  if (which == 2) {
    // --- cheap scores c/b/m ---
    float* rc_l = (float*)smem;
    float* rm_l = rc_l + 128;
    float* vc_l = rm_l + 128;
    float* vm_l = vc_l + 128;
    float* hr_l = vm_l + 128;
    if (tid < 128) {
      rc_l[tid] = a.Rc[(size_t)bi * 128 + tid];
      rm_l[tid] = a.Rm[(size_t)bi * 128 + tid];
      vc_l[tid] = a.vcf[tid];
      vm_l[tid] = a.vmf[tid];
    }
    hr_l[tid] = a.hrf[(size_t)bi * 256 + tid];
    __syncthreads();
    int j = tid;
    const float4* hc4 = (const float4*)(a.Hc + (size_t)(b * 256 + j) * 128);
    const float4* hm4 = (const float4*)(a.Hm + (size_t)(b * 256 + j) * 128);
    const float4* hb4 = (const float4*)(a.HB + (size_t)(b * 256 + j) * 256);
    const float4* rc4 = (const float4*)rc_l;
    const float4* rm4 = (const float4*)rm_l;
    const float4* vc4 = (const float4*)vc_l;
    const float4* vm4 = (const float4*)vm_l;
    const float4* hr4 = (const float4*)hr_l;
    float sc = 0.f, sm = 0.f, sb2 = 0.f;
    #pragma unroll 4
    for (int k = 0; k < 32; ++k) {
      float4 x = hc4[k], c = rc4[k], v = vc4[k];
      sc += v.x * tanh_f(x.x + c.x) + v.y * tanh_f(x.y + c.y)
          + v.z * tanh_f(x.z + c.z) + v.w * tanh_f(x.w + c.w);
      float4 am = hm4[k], cm = rm4[k], vv = vm4[k];
      sm += vv.x * tanh_f(am.x - cm.x) + vv.y * tanh_f(am.y - cm.y)
          + vv.z * tanh_f(am.z - cm.z) + vv.w * tanh_f(am.w - cm.w);
    }
    #pragma unroll 4
    for (int k = 0; k < 64; ++k) {
      float4 p = hb4[k], h = hr4[k];
      sb2 += p.x * h.x + p.y * h.y + p.z * h.z + p.w * h.w;
    }
    size_t o = (size_t)bi * 256 + j;
    a.S[(size_t)STY * 1 + o] = sc;
    a.S[(size_t)STY * 3 + o] = sb2;
    a.S[(size_t)STY * 4 + o] = sm;
    return;
  }
  // --- expensive scores d/s ---
  const unsigned short* Xhi = a.Xhi[which];
  const float* W = a.Wt[which];
  const float* v = a.vt[which];
  float* Sout = a.So[which];
  unsigned short* w_lds = (unsigned short*)smem;
  float* sp = (float*)smem;
  int lane = tid & 63, w = tid >> 6, quad = lane >> 4, l16 = lane & 15;
  int kh = w & 1, jh = w >> 1;
  int d4 = tid & 63, rhi = tid >> 6;
  float4 h4 = ((const float4*)(a.Rf + (size_t)bi * 256))[d4];
  #pragma unroll
  for (int it = 0; it < 32; ++it) {
    int kl = it * 4 + rhi;
    float4 w4 = ((const float4*)(W + (size_t)kl * 256))[d4];
    unsigned long long pk =
        (unsigned long long)f2b(w4.x * h4.x)
      | ((unsigned long long)f2b(w4.y * h4.y) << 16)
      | ((unsigned long long)f2b(w4.z * h4.z) << 32)
      | ((unsigned long long)f2b(w4.w * h4.w) << 48);
    int gphys = ((d4 >> 1) + kl) & 31;
    *(unsigned long long*)(w_lds + (size_t)kl * 256 + gphys * 8 + (d4 & 1) * 4) = pk;
  }
  BAR_LGKM();
  s16x8 afr[4][8];
  #pragma unroll
  for (int c = 0; c < 4; ++c) {
    int krow = kh * 64 + c * 16 + l16;
    #pragma unroll
    for (int kc = 0; kc < 8; ++kc) {
      int gp = (kc * 4 + quad + krow) & 31;
      afr[c][kc] = ldfrag(w_lds + (size_t)krow * 256 + gp * 8);
    }
  }
  float vv[4][4];
  #pragma unroll
  for (int c = 0; c < 4; ++c)
    #pragma unroll
    for (int r = 0; r < 4; ++r) vv[c][r] = v[kh * 64 + c * 16 + quad * 4 + r];
  BAR_LGKM();
  #pragma unroll
  for (int jj = 0; jj < 8; ++jj) {
    int jt = jh * 8 + jj;
    const unsigned short* Xp = Xhi + (size_t)(b * 256 + jt * 16 + l16) * 256 + quad * 8;
    s16x8 bf[8];
    #pragma unroll
    for (int kc = 0; kc < 8; ++kc) bf[kc] = ldfrag(Xp + kc * 32);
    f32x4 acc[4];
    #pragma unroll
    for (int c = 0; c < 4; ++c) acc[c] = f32x4{0.f, 0.f, 0.f, 0.f};
    #pragma unroll
    for (int kc = 0; kc < 8; ++kc) {
      #pragma unroll
      for (int c = 0; c < 4; ++c) acc[c] = mfma16(afr[c][kc], bf[kc], acc[c]);
    }
    float s = 0.f;
    #pragma unroll
    for (int c = 0; c < 4; ++c)
      #pragma unroll
      for (int r = 0; r < 4; ++r) s += tanh_f(acc[c][r]) * vv[c][r];
    s += __shfl_xor(s, 16);
    s += __shfl_xor(s, 32);
    if (lane < 16) sp[kh * 256 + jt * 16 + l16] = s;
  }
  BAR_LGKM();
  Sout[(size_t)bi * 256 + tid] = sp[tid] + sp[256 + tid];
}

// ---------------- wsum with inline softmax ----------------

__global__ __launch_bounds__(256) void k_wsum(const float* __restrict__ S,
    const float* __restrict__ hl_f, const float* __restrict__ hr_f,
    unsigned short* __restrict__ ahi, unsigned short* __restrict__ alo) {
  int it = blockIdx.x, type = blockIdx.y, b = blockIdx.z;
  __shared__ float p_l[8][256];
  __shared__ float red[4];
  int tid = threadIdx.x;
  for (int ii = 0; ii < 8; ++ii) {
    size_t o = (size_t)type * STY + ((size_t)(b * 256 + it * 8 + ii)) * 256 + tid;
    float x = S[o];
    float m = x;
    for (int dl = 32; dl; dl >>= 1) m = fmaxf(m, __shfl_xor(m, dl));
    if ((tid & 63) == 0) red[tid >> 6] = m;
    __syncthreads();
    m = fmaxf(fmaxf(red[0], red[1]), fmaxf(red[2], red[3]));
    __syncthreads();
    float e = __expf(x - m);
    float sum = e;
    for (int dl = 32; dl; dl >>= 1) sum += __shfl_xor(sum, dl);
    if ((tid & 63) == 0) red[tid >> 6] = sum;
    __syncthreads();
    sum = red[0] + red[1] + red[2] + red[3];
    p_l[ii][tid] = e / sum;
    __syncthreads();
  }
  const float* src = (type == 0 ? hr_f : hl_f) + (size_t)b * 256 * 256;
  float acc[8] = {0.f, 0.f, 0.f, 0.f, 0.f, 0.f, 0.f, 0.f};
  for (int j = 0; j < 256; ++j) {
    float hv = src[(size_t)j * 256 + tid];
    #pragma unroll
    for (int ii = 0; ii < 8; ++ii) acc[ii] += p_l[ii][j] * hv;
  }
  int off = 256 * (1 + type);      // agg: [hr | pts | ptc | ptd | ptb | ptm]
  #pragma unroll
  for (int ii = 0; ii < 8; ++ii) {
    float vv = acc[ii];
    unsigned short hi = f2b(vv);
    size_t o = (size_t)(b * 256 + it * 8 + ii) * H12 + off + tid;
    ahi[o] = hi;
    alo[o] = f2b(vv - b2f(hi));
  }
}

// ---------------- fused tail ----------------

__global__ __launch_bounds__(256) void k_tail(const float* __restrict__ Hp,
    const float* __restrict__ hl_f, const float* __restrict__ vpf,
    const float* __restrict__ Wc2f, const float* __restrict__ Arc,
    const float* __restrict__ ar_f, const float* __restrict__ vcf,
    const float* __restrict__ Wpredf, float* __restrict__ out) {
  int b = blockIdx.x, tid = threadIdx.x;
  __shared__ float vl[128], wl[256], rvec[256], rlcl[128], red[4];
  if (tid < 128) vl[tid] = vpf[tid];
  __syncthreads();
  const float* hp = Hp + (size_t)(b * 256 + tid) * 128;
  float s = 0.f;
  for (int k = 0; k < 128; ++k) s += vl[k] * tanh_f(hp[k]);
  float m = s;
  for (int dl = 32; dl; dl >>= 1) m = fmaxf(m, __shfl_xor(m, dl));
  if ((tid & 63) == 0) red[tid >> 6] = m;
  __syncthreads();
  m = fmaxf(fmaxf(red[0], red[1]), fmaxf(red[2], red[3]));
  __syncthreads();
  float e = __expf(s - m);
  float sum = e;
  for (int dl = 32; dl; dl >>= 1) sum += __shfl_xor(sum, dl);
  if ((tid & 63) == 0) red[tid >> 6] = sum;
  __syncthreads();
  sum = red[0] + red[1] + red[2] + red[3];
  wl[tid] = e / sum;
  __syncthreads();
  float acc = 0.f;
  for (int t = 0; t < 256; ++t) acc += wl[t] * hl_f[(size_t)(b * 256 + t) * 256 + tid];
  rvec[tid] = acc;
  __syncthreads();
  if (tid < 128) {
    float a2 = 0.f;
    const float* wr = Wc2f + (size_t)tid * 256;
    for (int dk = 0; dk < 256; ++dk) a2 += rvec[dk] * wr[dk];
    rlcl[tid] = a2;
    vl[tid] = vcf[tid];
  }
  __syncthreads();
  const float* ap = Arc + (size_t)(b * 256 + tid) * 128;
  float s2 = 0.f;
  for (int k = 0; k < 128; ++k) s2 += vl[k] * (ap[k] + rlcl[k]);
  m = s2;
  for (int dl = 32; dl; dl >>= 1) m = fmaxf(m, __shfl_xor(m, dl));
  if ((tid & 63) == 0) red[tid >> 6] = m;
  __syncthreads();
  m = fmaxf(fmaxf(red[0], red[1]), fmaxf(red[2], red[3]));
  __syncthreads();
  float e2 = __expf(s2 - m);
  float sum2 = e2;
  for (int dl = 32; dl; dl >>= 1) sum2 += __shfl_xor(sum2, dl);
  if ((tid & 63) == 0) red[tid >> 6] = sum2;
  __syncthreads();
  sum2 = red[0] + red[1] + red[2] + red[3];
  wl[tid] = e2 / sum2;
  __syncthreads();
  float acc2 = 0.f;
  for (int t = 0; t < 256; ++t) acc2 += wl[t] * ar_f[(size_t)(b * 256 + t) * 256 + tid];
  rvec[tid] = acc2;
  __syncthreads();
  if (tid < 2) {
    float o = 0.f;
    const float* wp = Wpredf + (size_t)tid * 256;
    for (int dk = 0; dk < 256; ++dk) o += rvec[dk] * wp[dk];
    out[b * 2 + tid] = sigm(o);
  }
}

// ---------------- host ----------------

extern "C" void kernel_launch(void* const* d_in, const int* in_sizes, int n_in,
                              void* d_out, int out_size, void* d_ws, size_t ws_size,
                              hipStream_t stream) {
  (void)in_sizes; (void)n_in; (void)out_size; (void)ws_size;
  const int* inputs = (const int*)d_in[0];
  const float* embed = (const float*)d_in[1];
  const float* lWih = (const float*)d_in[2];
  const float* lWhh = (const float*)d_in[3];
  const float* lbih = (const float*)d_in[4];
  const float* lbhh = (const float*)d_in[5];
  const float* rWih = (const float*)d_in[6];
  const float* rWhh = (const float*)d_in[7];
  const float* rbih = (const float*)d_in[8];
  const float* rbhh = (const float*)d_in[9];
  const float* aWih = (const float*)d_in[10];
  const float* aWhh = (const float*)d_in[11];
  const float* abih = (const float*)d_in[12];
  const float* abhh = (const float*)d_in[13];
  const float* Wc1 = (const float*)d_in[14];
  const float* Wc2 = (const float*)d_in[15];
  const float* vc  = (const float*)d_in[16];
  const float* Wb  = (const float*)d_in[17];
  const float* Wd  = (const float*)d_in[18];
  const float* vd  = (const float*)d_in[19];
  const float* Wm  = (const float*)d_in[20];
  const float* vmv = (const float*)d_in[21];
  const float* Wsw = (const float*)d_in[22];
  const float* vsv = (const float*)d_in[23];
  const float* Wp  = (const float*)d_in[24];
  const float* vp  = (const float*)d_in[25];
  const float* Wpred = (const float*)d_in[26];

  char* ws = (char*)d_ws;
  size_t off = 0;
  auto alloc = [&](size_t bytes) -> void* {
    void* p = ws + off;
    off += (bytes + 255) & ~(size_t)255;
    return p;
  };
  unsigned short* xhi = (unsigned short*)alloc((size_t)M * EP * 2);
  unsigned short* xlo = (unsigned short*)alloc((size_t)M * EP * 2);
  unsigned short* wpad = (unsigned short*)alloc((size_t)4 * H3 * EP * 2);
  unsigned short* Whh_b = (unsigned short*)alloc((size_t)6 * H3 * H * 2);
  unsigned short* aWih_b = (unsigned short*)alloc((size_t)2 * H3 * H12 * 2);
  unsigned short* Wc1_b = (unsigned short*)alloc((size_t)H * H2 * 2);
  unsigned short* Wc2_b = (unsigned short*)alloc((size_t)H * H2 * 2);
  unsigned short* Wm_b  = (unsigned short*)alloc((size_t)H * H2 * 2);
  unsigned short* Wp_b  = (unsigned short*)alloc((size_t)H * H2 * 2);
  unsigned short* Wb_b  = (unsigned short*)alloc((size_t)H2 * H2 * 2);
  char* region1 = (char*)alloc((size_t)4 * M * H3 * 4);
  float* pre_lr = (float*)region1;
  float* S      = (float*)region1;
  float* pre_a  = (float*)region1;
  float* hl_f = (float*)alloc((size_t)M * H2 * 4);
  float* hr_f = (float*)alloc((size_t)M * H2 * 4);
  unsigned short* hl_hi = (unsigned short*)alloc((size_t)M * H2 * 2);
  unsigned short* hl_lo = (unsigned short*)alloc((size_t)M * H2 * 2);
  unsigned short* hr_hi = (unsigned short*)alloc((size_t)M * H2 * 2);
  unsigned short* hr_lo = (unsigned short*)alloc((size_t)M * H2 * 2);
  float* Hc = (float*)alloc((size_t)M * H * 4);
  float* Rc = (float*)alloc((size_t)M * H * 4);
  float* Hm = (float*)alloc((size_t)M * H * 4);
  float* Rm = (float*)alloc((size_t)M * H * 4);
  float* Hp = (float*)alloc((size_t)M * H * 4);
  float* HB = (float*)alloc((size_t)M * H2 * 4);
  unsigned short* agg_hi = (unsigned short*)alloc((size_t)M * H12 * 2);
  unsigned short* agg_lo = (unsigned short*)alloc((size_t)M * H12 * 2);
  float* ar_f = (float*)alloc((size_t)M * H2 * 4);
  unsigned short* ar_hi = (unsigned short*)alloc((size_t)M * H2 * 2);
  unsigned short* ar_lo = (unsigned short*)alloc((size_t)M * H2 * 2);
  float* Arc = (float*)alloc((size_t)M * H * 4);

  // 1. staging
  StageArgs sa{};
  sa.cs[0] = lWhh;  sa.cd[0] = Whh_b;                 sa.cn[0] = 2 * H3 * H;
  sa.cs[1] = rWhh;  sa.cd[1] = Whh_b + 2 * H3 * H;    sa.cn[1] = 2 * H3 * H;
  sa.cs[2] = aWhh;  sa.cd[2] = Whh_b + 4 * H3 * H;    sa.cn[2] = 2 * H3 * H;
  sa.cs[3] = aWih;  sa.cd[3] = aWih_b;                sa.cn[3] = 2 * H3 * H12;
  sa.cs[4] = Wc1;   sa.cd[4] = Wc1_b;                 sa.cn[4] = H * H2;
  sa.cs[5] = Wc2;   sa.cd[5] = Wc2_b;                 sa.cn[5] = H * H2;
  sa.cs[6] = Wm;    sa.cd[6] = Wm_b;                  sa.cn[6] = H * H2;
  sa.cs[7] = Wp;    sa.cd[7] = Wp_b;                  sa.cn[7] = H * H2;
  sa.cs[8] = Wb;    sa.cd[8] = Wb_b;                  sa.cn[8] = H2 * H2;
  sa.idx = inputs; sa.emb = embed; sa.xhi = xhi; sa.xlo = xlo;
  sa.lW = lWih; sa.rW = rWih; sa.wpad = wpad;
  k_stage<<<dim3((2 * H3 * H12 + 255) / 256, 11), dim3(256), 0, stream>>>(sa);

  // 2. input projections for l/r GRUs
  GemmBatch ga{};
  const float* biases[4] = { lbih, lbih + H3, rbih, rbih + H3 };
  for (int u = 0; u < 4; ++u)
    ga.d[u] = GemmDesc{ xhi, xlo, wpad + (size_t)u * H3 * EP, biases[u],
                        pre_lr + (size_t)u * M * H3, H3, EP };
  k_gemm<<<dim3(16, 6, 4), dim3(256), 0, stream>>>(ga);

  // 3. l/r recurrences (writes fp32 + hi/lo + agg hr-copy)
  RecArgs r1{};
  r1.whh[0] = Whh_b;               r1.whh[1] = Whh_b + H3 * H;
  r1.whh[2] = Whh_b + 2 * H3 * H;  r1.whh[3] = Whh_b + 3 * H3 * H;
  for (int u = 0; u < 4; ++u) r1.pre[u] = pre_lr + (size_t)u * M * H3;
  r1.outf[0] = r1.outf[1] = hl_f; r1.outf[2] = r1.outf[3] = hr_f;
  r1.outhi[0] = r1.outhi[1] = hl_hi; r1.outhi[2] = r1.outhi[3] = hr_hi;
  r1.outlo[0] = r1.outlo[1] = hl_lo; r1.outlo[2] = r1.outlo[3] = hr_lo;
  r1.agghi[0] = r1.agghi[1] = nullptr; r1.agghi[2] = r1.agghi[3] = agg_hi;
  r1.agglo[0] = r1.agglo[1] = nullptr; r1.agglo[2] = r1.agglo[3] = agg_lo;
  r1.bhh[0] = lbhh; r1.bhh[1] = lbhh + H3; r1.bhh[2] = rbhh; r1.bhh[3] = rbhh + H3;
  r1.colOff[0] = 0; r1.colOff[1] = H; r1.colOff[2] = 0; r1.colOff[3] = H;
  r1.dir[0] = 0; r1.dir[1] = 1; r1.dir[2] = 0; r1.dir[3] = 1;
  k_gru<<<dim3(4), dim3(256), 0, stream>>>(r1);

  // 4. projection GEMMs
  GemmBatch gbB{};
  gbB.d[0] = GemmDesc{ hl_hi, hl_lo, Wc1_b, nullptr, Hc, H, H2 };
  gbB.d[1] = GemmDesc{ hr_hi, hr_lo, Wc2_b, nullptr, Rc, H, H2 };
  gbB.d[2] = GemmDesc{ hl_hi, hl_lo, Wm_b, nullptr, Hm, H, H2 };
  gbB.d[3] = GemmDesc{ hr_hi, hr_lo, Wm_b, nullptr, Rm, H, H2 };
  gbB.d[4] = GemmDesc{ hl_hi, hl_lo, Wb_b, nullptr, HB, H2, H2 };
  gbB.d[5] = GemmDesc{ hl_hi, hl_lo, Wp_b, nullptr, Hp, H, H2 };
  k_gemm<<<dim3(16, 4, 6), dim3(256), 0, stream>>>(gbB);

  // 5. all scores (one dispatch)
  ScArgs sc{};
  sc.Xhi[0] = hl_hi; sc.Wt[0] = Wd;  sc.vt[0] = vd;  sc.So[0] = S + (size_t)2 * STY;
  sc.Xhi[1] = hr_hi; sc.Wt[1] = Wsw; sc.vt[1] = vsv; sc.So[1] = S + (size_t)0 * STY;
  sc.Rf = hr_f;
  sc.Hc = Hc; sc.Rc = Rc; sc.Hm = Hm; sc.Rm = Rm; sc.HB = HB;
  sc.hrf = hr_f; sc.vcf = vc; sc.vmf = vmv; sc.S = S;
  k_score<<<dim3(M, 3), dim3(256), 0, stream>>>(sc);

  // 6. softmax + weighted sums into agg
  k_wsum<<<dim3(32, 5, 4), dim3(256), 0, stream>>>(S, hl_f, hr_f, agg_hi, agg_lo);

  // 7. agg GRU input projection
  GemmBatch gc{};
  gc.d[0] = GemmDesc{ agg_hi, agg_lo, aWih_b, abih, pre_a, H3, H12 };
  gc.d[1] = GemmDesc{ agg_hi, agg_lo, aWih_b + (size_t)H3 * H12, abih + H3,
                      pre_a + (size_t)M * H3, H3, H12 };
  k_gemm<<<dim3(16, 6, 2), dim3(256), 0, stream>>>(gc);

  // 8. agg recurrence (writes ar fp32 + hi/lo)
  RecArgs r2{};
  r2.whh[0] = Whh_b + 4 * H3 * H; r2.whh[1] = Whh_b + 5 * H3 * H;
  r2.whh[2] = r2.whh[3] = Whh_b + 4 * H3 * H;
  r2.pre[0] = pre_a; r2.pre[1] = pre_a + (size_t)M * H3;
  r2.pre[2] = r2.pre[3] = pre_a;
  r2.outf[0] = r2.outf[1] = r2.outf[2] = r2.outf[3] = ar_f;
  r2.outhi[0] = r2.outhi[1] = r2.outhi[2] = r2.outhi[3] = ar_hi;
  r2.outlo[0] = r2.outlo[1] = r2.outlo[2] = r2.outlo[3] = ar_lo;
  for (int u = 0; u < 4; ++u) { r2.agghi[u] = nullptr; r2.agglo[u] = nullptr; }
  r2.bhh[0] = abhh; r2.bhh[1] = abhh + H3; r2.bhh[2] = r2.bhh[3] = abhh;
  r2.colOff[0] = 0; r2.colOff[1] = H; r2.colOff[2] = r2.colOff[3] = 0;
  r2.dir[0] = 0; r2.dir[1] = 1; r2.dir[2] = r2.dir[3] = 0;
  k_gru<<<dim3(2), dim3(256), 0, stream>>>(r2);

  // 9. Arc GEMM
  GemmBatch gd{};
  gd.d[0] = GemmDesc{ ar_hi, ar_lo, Wc1_b, nullptr, Arc, H, H2 };
  k_gemm<<<dim3(16, 2, 1), dim3(256), 0, stream>>>(gd);

  // 10. fused tail
  k_tail<<<dim3(4), dim3(256), 0, stream>>>(Hp, hl_f, vp, Wc2, Arc, ar_f, vc, Wpred,
                                            (float*)d_out);
}

// Round 9
// 793.792 us; speedup vs baseline: 1.1419x; 1.1419x over previous
//
#include <hip/hip_runtime.h>

// MANNet forward, MI355X gfx950. Inputs fp32 (+int32 ids), output fp32.
// R9: k_gru v3 — 512 threads / 8 waves (2 waves/SIMD to hide dep-VALU latency),
// 1 h-value per thread, wave-local gh exchange, 1 lgkm barrier/step.

#define DEV static __device__ __forceinline__
#define BAR_LGKM() __asm__ volatile("s_waitcnt lgkmcnt(0)\ns_barrier" ::: "memory")

typedef __attribute__((ext_vector_type(4))) float f32x4;
typedef __attribute__((ext_vector_type(8))) short s16x8;
typedef __attribute__((ext_vector_type(4))) unsigned int u32x4;

constexpr int T = 256, E = 300, EP = 320, H = 128, H2 = 256, H3 = 384, H12 = 1536;
constexpr int M = 1024;            // B*T
constexpr int STY = 262144;        // 4*T*T elements per score type

DEV float b2f(unsigned short h) { return __uint_as_float(((unsigned)h) << 16); }
DEV unsigned short f2b(float f) {
  unsigned u = __float_as_uint(f);
  u += 0x7fff + ((u >> 16) & 1);            // RNE
  return (unsigned short)(u >> 16);
}
DEV float sigm(float x) { return 1.f / (1.f + __expf(-x)); }
DEV float tanh_f(float x) { float e = __expf(2.f * x); return 1.f - 2.f / (e + 1.f); }

DEV s16x8 ldfrag(const unsigned short* p) {
  u32x4 v = *(const u32x4*)p;
  return __builtin_bit_cast(s16x8, v);
}
DEV f32x4 mfma16(s16x8 a, s16x8 b, f32x4 c) {
  return __builtin_amdgcn_mfma_f32_16x16x32_bf16(a, b, c, 0, 0, 0);
}

// ---------------- fused staging: 9x cvt + embed + padw ----------------

struct StageArgs {
  const float* cs[9]; unsigned short* cd[9]; int cn[9];
  const int* idx; const float* emb; unsigned short* xhi; unsigned short* xlo;
  const float* lW; const float* rW; unsigned short* wpad;
};

__global__ void k_stage(StageArgs sa) {
  int seg = blockIdx.y;
  int i = blockIdx.x * 256 + threadIdx.x;
  if (seg < 9) {
    if (i < sa.cn[seg]) sa.cd[seg][i] = f2b(sa.cs[seg][i]);
    return;
  }
  if (seg == 9) {
    if (i >= M * EP) return;
    int m = i / EP, e = i - m * EP;
    int r = sa.idx[m];
    float v = (e < E) ? sa.emb[(size_t)r * E + e] : 0.f;
    unsigned short hi = f2b(v);
    sa.xhi[i] = hi;
    sa.xlo[i] = f2b(v - b2f(hi));
    return;
  }
  if (i >= 4 * H3 * EP) return;
  int e = i % EP, n = (i / EP) % H3, uu = i / (EP * H3);
  const float* src = (uu < 2 ? sa.lW : sa.rW) + (size_t)((uu & 1) * H3 + n) * E;
  sa.wpad[i] = (e < E) ? f2b(src[e]) : (unsigned short)0;
}

// ---------------- generic GEMM: C = (Ahi+Alo) @ W^T (+bias), fp32 out ----------

struct GemmDesc {
  const unsigned short* Ahi; const unsigned short* Alo; const unsigned short* W;
  const float* bias; float* Cf; int N; int K;
};
struct GemmBatch { GemmDesc d[8]; };

__global__ __launch_bounds__(256) void k_gemm(GemmBatch gb) {
  GemmDesc g = gb.d[blockIdx.z];
  int nb = blockIdx.y * 64;
  if (nb >= g.N) return;
  int mb = blockIdx.x * 64;
  int lane = threadIdx.x & 63, w = threadIdx.x >> 6, quad = lane >> 4, l16 = lane & 15;
  int K = g.K;
  const unsigned short* Ahp = g.Ahi + (size_t)(mb + w * 16 + l16) * K + quad * 8;
  const unsigned short* Alp = g.Alo + (size_t)(mb + w * 16 + l16) * K + quad * 8;
  const unsigned short* Wp = g.W + (size_t)(nb + l16) * K + quad * 8;
  f32x4 acc[4];
  #pragma unroll
  for (int nt = 0; nt < 4; ++nt) acc[nt] = f32x4{0.f, 0.f, 0.f, 0.f};
  for (int k = 0; k < K; k += 32) {
    s16x8 ah = ldfrag(Ahp + k);
    s16x8 al = ldfrag(Alp + k);
    #pragma unroll
    for (int nt = 0; nt < 4; ++nt) {
      s16x8 b = ldfrag(Wp + (size_t)nt * 16 * K + k);
      acc[nt] = mfma16(ah, b, acc[nt]);
      acc[nt] = mfma16(al, b, acc[nt]);
    }
  }
  int mr0 = mb + w * 16 + quad * 4;
  #pragma unroll
  for (int nt = 0; nt < 4; ++nt) {
    int col = nb + nt * 16 + l16;
    float bv = g.bias ? g.bias[col] : 0.f;
    #pragma unroll
    for (int r = 0; r < 4; ++r)
      g.Cf[(size_t)(mr0 + r) * g.N + col] = acc[nt][r] + bv;
  }
}

// ---------------- GRU recurrence v3: 8 waves, 1 h/thread ----------------
// Wave w owns Whh rows g*128 + w*16 + l16 (3 tiles). Gate thread: b=quad,
// d=w*16+l16 (wave-local gh exchange -> lgkmcnt-only mid-step). gh2 col-major
// pitch 10: gh2[(g*128+d)*10 + row], rows 0-3 hi batches, 4-7 lo.

struct RecArgs {
  const unsigned short* whh[4];
  const float* pre[4];
  float* outf[4];
  unsigned short* outhi[4];
  unsigned short* outlo[4];
  unsigned short* agghi[4];      // null -> no agg copy
  unsigned short* agglo[4];
  const float* bhh[4];
  int colOff[4];
  int dir[4];
};

__global__ __launch_bounds__(512) void k_gru(RecArgs ra) {
  int u = blockIdx.x;
  __shared__ __align__(16) unsigned short hs[2][16 * 136];
  __shared__ __align__(16) float gh2[384 * 10];
  int tid = threadIdx.x, lane = tid & 63, w = tid >> 6;
  int quad = lane >> 4, l16 = lane & 15;
  for (int i = tid; i < 2 * 16 * 136; i += 512) ((unsigned short*)hs)[i] = 0;
  const unsigned short* whh = ra.whh[u];
  s16x8 bq[3][4];
  #pragma unroll
  for (int g = 0; g < 3; ++g) {
    int row = g * 128 + w * 16 + l16;
    #pragma unroll
    for (int kc = 0; kc < 4; ++kc)
      bq[g][kc] = ldfrag(whh + (size_t)row * H + kc * 32 + quad * 8);
  }
  const float* bhh = ra.bhh[u];
  const float* pre = ra.pre[u];
  float* outf = ra.outf[u];
  unsigned short* outhi = ra.outhi[u];
  unsigned short* outlo = ra.outlo[u];
  unsigned short* agghi = ra.agghi[u];
  unsigned short* agglo = ra.agglo[u];
  int colOff = ra.colOff[u], dir = ra.dir[u];
  int b = quad, d = w * 16 + l16;
  float bh_r = bhh[d], bh_z = bhh[d + 128], bh_n = bhh[d + 256];
  float hf = 0.f;
  float ob[8];
  int t0 = dir ? (T - 1) : 0;
  const float* q0 = pre + (size_t)(b * T + t0) * H3 + d;
  float n_pr = q0[0], n_pz = q0[128], n_pn = q0[256];
  __syncthreads();
  for (int sb = 0; sb < T; sb += 8) {
    #pragma unroll
    for (int ss = 0; ss < 8; ++ss) {
      int s = sb + ss;
      float pr = n_pr, pz = n_pz, pn = n_pn;
      int sn = (s + 1 < T) ? (s + 1) : s;
      int tn = dir ? (T - 1 - sn) : sn;
      const float* f0 = pre + (size_t)(b * T + tn) * H3 + d;
      n_pr = f0[0]; n_pz = f0[128]; n_pn = f0[256];
      const unsigned short* hcur = hs[ss & 1];
      unsigned short* hnxt = hs[(ss & 1) ^ 1];
      s16x8 ah[4];
      #pragma unroll
      for (int kc = 0; kc < 4; ++kc)
        ah[kc] = ldfrag(hcur + l16 * 136 + kc * 32 + quad * 8);
      f32x4 acc[3];
      #pragma unroll
      for (int g = 0; g < 3; ++g) acc[g] = f32x4{0.f, 0.f, 0.f, 0.f};
      #pragma unroll
      for (int kc = 0; kc < 4; ++kc) {
        #pragma unroll
        for (int g = 0; g < 3; ++g)
          acc[g] = mfma16(ah[kc], bq[g][kc], acc[g]);
      }
      if (quad < 2) {                       // quad0: hi rows 0-3, quad1: lo 4-7
        #pragma unroll
        for (int g = 0; g < 3; ++g) {
          float2* p = (float2*)(gh2 + ((size_t)(g * 128 + w * 16 + l16)) * 10 + quad * 4);
          p[0] = float2{acc[g][0], acc[g][1]};
          p[1] = float2{acc[g][2], acc[g][3]};
        }
      }
      __asm__ volatile("s_waitcnt lgkmcnt(0)" ::: "memory");   // wave-local
      const float* g0 = gh2 + ((size_t)(0 * 128 + d)) * 10;
      const float* g1 = gh2 + ((size_t)(1 * 128 + d)) * 10;
      const float* g2 = gh2 + ((size_t)(2 * 128 + d)) * 10;
      float rr = g0[b] + g0[4 + b];
      float zz = g1[b] + g1[4 + b];
      float nn = g2[b] + g2[4 + b];
      float rg = sigm(pr + rr + bh_r);
      float zg = sigm(pz + zz + bh_z);
      float ng = tanh_f(pn + rg * (nn + bh_n));
      hf = (1.f - zg) * ng + zg * hf;
      unsigned short hi = f2b(hf);
      hnxt[b * 136 + d] = hi;
      hnxt[(4 + b) * 136 + d] = f2b(hf - b2f(hi));
      ob[ss] = hf;
      BAR_LGKM();                           // cross-wave h exchange
    }
    #pragma unroll
    for (int qq = 0; qq < 8; ++qq) {
      int sq = sb + qq;
      int tq = dir ? (T - 1 - sq) : sq;
      float v = ob[qq];
      unsigned short h0 = f2b(v);
      unsigned short l0 = f2b(v - b2f(h0));
      size_t o = (size_t)(b * T + tq) * H2 + colOff + d;
      outf[o] = v; outhi[o] = h0; outlo[o] = l0;
      if (agghi) {
        size_t a = (size_t)(b * T + tq) * H12 + colOff + d;
        agghi[a] = h0; agglo[a] = l0;
      }
    }
  }
}

// ---------------- scores (merged): y=0,1 -> ds; y=2 -> cmb ----------------

struct ScArgs {
  const unsigned short* Xhi[2];
  const float* Rf; const float* Wt[2]; const float* vt[2]; float* So[2];
  const float *Hc, *Rc, *Hm, *Rm, *HB, *hrf, *vcf, *vmf; float* S;
};

__global__ __launch_bounds__(256, 2) void k_score(ScArgs a) {
  __shared__ __align__(16) unsigned char smem[65536];
  int which = blockIdx.y;
  int bi = blockIdx.x, b = bi >> 8;
  int tid = threadIdx.x;
  if (which == 2) {
    float* rc_l = (float*)smem;
    float* rm_l = rc_l + 128;
    float* vc_l = rm_l + 128;
    float* vm_l = vc_l + 128;
    float* hr_l = vm_l + 128;
    if (tid < 128) {
      rc_l[tid] = a.Rc[(size_t)bi * 128 + tid];
      rm_l[tid] = a.Rm[(size_t)bi * 128 + tid];
      vc_l[tid] = a.vcf[tid];
      vm_l[tid] = a.vmf[tid];
    }
    hr_l[tid] = a.hrf[(size_t)bi * 256 + tid];
    __syncthreads();
    int j = tid;
    const float4* hc4 = (const float4*)(a.Hc + (size_t)(b * 256 + j) * 128);
    const float4* hm4 = (const float4*)(a.Hm + (size_t)(b * 256 + j) * 128);
    const float4* hb4 = (const float4*)(a.HB + (size_t)(b * 256 + j) * 256);
    const float4* rc4 = (const float4*)rc_l;
    const float4* rm4 = (const float4*)rm_l;
    const float4* vc4 = (const float4*)vc_l;
    const float4* vm4 = (const float4*)vm_l;
    const float4* hr4 = (const float4*)hr_l;
    float sc = 0.f, sm = 0.f, sb2 = 0.f;
    #pragma unroll 4
    for (int k = 0; k < 32; ++k) {
      float4 x = hc4[k], c = rc4[k], v = vc4[k];
      sc += v.x * tanh_f(x.x + c.x) + v.y * tanh_f(x.y + c.y)
          + v.z * tanh_f(x.z + c.z) + v.w * tanh_f(x.w + c.w);
      float4 am = hm4[k], cm = rm4[k], vv = vm4[k];
      sm += vv.x * tanh_f(am.x - cm.x) + vv.y * tanh_f(am.y - cm.y)
          + vv.z * tanh_f(am.z - cm.z) + vv.w * tanh_f(am.w - cm.w);
    }
    #pragma unroll 4
    for (int k = 0; k < 64; ++k) {
      float4 p = hb4[k], h = hr4[k];
      sb2 += p.x * h.x + p.y * h.y + p.z * h.z + p.w * h.w;
    }
    size_t o = (size_t)bi * 256 + j;
    a.S[(size_t)STY * 1 + o] = sc;
    a.S[(size_t)STY * 3 + o] = sb2;
    a.S[(size_t)STY * 4 + o] = sm;
    return;
  }
  const unsigned short* Xhi = a.Xhi[which];
  const float* W = a.Wt[which];
  const float* v = a.vt[which];
  float* Sout = a.So[which];
  unsigned short* w_lds = (unsigned short*)smem;
  float* sp = (float*)smem;
  int lane = tid & 63, w = tid >> 6, quad = lane >> 4, l16 = lane & 15;
  int kh = w & 1, jh = w >> 1;
  int d4 = tid & 63, rhi = tid >> 6;
  float4 h4 = ((const float4*)(a.Rf + (size_t)bi * 256))[d4];
  #pragma unroll
  for (int it = 0; it < 32; ++it) {
    int kl = it * 4 + rhi;
    float4 w4 = ((const float4*)(W + (size_t)kl * 256))[d4];
    unsigned long long pk =
        (unsigned long long)f2b(w4.x * h4.x)
      | ((unsigned long long)f2b(w4.y * h4.y) << 16)
      | ((unsigned long long)f2b(w4.z * h4.z) << 32)
      | ((unsigned long long)f2b(w4.w * h4.w) << 48);
    int gphys = ((d4 >> 1) + kl) & 31;
    *(unsigned long long*)(w_lds + (size_t)kl * 256 + gphys * 8 + (d4 & 1) * 4) = pk;
  }
  BAR_LGKM();
  s16x8 afr[4][8];
  #pragma unroll
  for (int c = 0; c < 4; ++c) {
    int krow = kh * 64 + c * 16 + l16;
    #pragma unroll
    for (int kc = 0; kc < 8; ++kc) {
      int gp = (kc * 4 + quad + krow) & 31;
      afr[c][kc] = ldfrag(w_lds + (size_t)krow * 256 + gp * 8);
    }
  }
  float vv[4][4];
  #pragma unroll
  for (int c = 0; c < 4; ++c)
    #pragma unroll
    for (int r = 0; r < 4; ++r) vv[c][r] = v[kh * 64 + c * 16 + quad * 4 + r];
  BAR_LGKM();
  #pragma unroll
  for (int jj = 0; jj < 8; ++jj) {
    int jt = jh * 8 + jj;
    const unsigned short* Xp = Xhi + (size_t)(b * 256 + jt * 16 + l16) * 256 + quad * 8;
    s16x8 bf[8];
    #pragma unroll
    for (int kc = 0; kc < 8; ++kc) bf[kc] = ldfrag(Xp + kc * 32);
    f32x4 acc[4];
    #pragma unroll
    for (int c = 0; c < 4; ++c) acc[c] = f32x4{0.f, 0.f, 0.f, 0.f};
    #pragma unroll
    for (int kc = 0; kc < 8; ++kc) {
      #pragma unroll
      for (int c = 0; c < 4; ++c) acc[c] = mfma16(afr[c][kc], bf[kc], acc[c]);
    }
    float s = 0.f;
    #pragma unroll
    for (int c = 0; c < 4; ++c)
      #pragma unroll
      for (int r = 0; r < 4; ++r) s += tanh_f(acc[c][r]) * vv[c][r];
    s += __shfl_xor(s, 16);
    s += __shfl_xor(s, 32);
    if (lane < 16) sp[kh * 256 + jt * 16 + l16] = s;
  }
  BAR_LGKM();
  Sout[(size_t)bi * 256 + tid] = sp[tid] + sp[256 + tid];
}

// ---------------- wsum with inline softmax ----------------

__global__ __launch_bounds__(256) void k_wsum(const float* __restrict__ S,
    const float* __restrict__ hl_f, const float* __restrict__ hr_f,
    unsigned short* __restrict__ ahi, unsigned short* __restrict__ alo) {
  int it = blockIdx.x, type = blockIdx.y, b = blockIdx.z;
  __shared__ float p_l[8][256];
  __shared__ float red[4];
  int tid = threadIdx.x;
  for (int ii = 0; ii < 8; ++ii) {
    size_t o = (size_t)type * STY + ((size_t)(b * 256 + it * 8 + ii)) * 256 + tid;
    float x = S[o];
    float m = x;
    for (int dl = 32; dl; dl >>= 1) m = fmaxf(m, __shfl_xor(m, dl));
    if ((tid & 63) == 0) red[tid >> 6] = m;
    __syncthreads();
    m = fmaxf(fmaxf(red[0], red[1]), fmaxf(red[2], red[3]));
    __syncthreads();
    float e = __expf(x - m);
    float sum = e;
    for (int dl = 32; dl; dl >>= 1) sum += __shfl_xor(sum, dl);
    if ((tid & 63) == 0) red[tid >> 6] = sum;
    __syncthreads();
    sum = red[0] + red[1] + red[2] + red[3];
    p_l[ii][tid] = e / sum;
    __syncthreads();
  }
  const float* src = (type == 0 ? hr_f : hl_f) + (size_t)b * 256 * 256;
  float acc[8] = {0.f, 0.f, 0.f, 0.f, 0.f, 0.f, 0.f, 0.f};
  for (int j = 0; j < 256; ++j) {
    float hv = src[(size_t)j * 256 + tid];
    #pragma unroll
    for (int ii = 0; ii < 8; ++ii) acc[ii] += p_l[ii][j] * hv;
  }
  int off = 256 * (1 + type);      // agg: [hr | pts | ptc | ptd | ptb | ptm]
  #pragma unroll
  for (int ii = 0; ii < 8; ++ii) {
    float vv = acc[ii];
    unsigned short hi = f2b(vv);
    size_t o = (size_t)(b * 256 + it * 8 + ii) * H12 + off + tid;
    ahi[o] = hi;
    alo[o] = f2b(vv - b2f(hi));
  }
}

// ---------------- fused tail ----------------

__global__ __launch_bounds__(256) void k_tail(const float* __restrict__ Hp,
    const float* __restrict__ hl_f, const float* __restrict__ vpf,
    const float* __restrict__ Wc2f, const float* __restrict__ Arc,
    const float* __restrict__ ar_f, const float* __restrict__ vcf,
    const float* __restrict__ Wpredf, float* __restrict__ out) {
  int b = blockIdx.x, tid = threadIdx.x;
  __shared__ float vl[128], wl[256], rvec[256], rlcl[128], red[4];
  if (tid < 128) vl[tid] = vpf[tid];
  __syncthreads();
  const float* hp = Hp + (size_t)(b * 256 + tid) * 128;
  float s = 0.f;
  for (int k = 0; k < 128; ++k) s += vl[k] * tanh_f(hp[k]);
  float m = s;
  for (int dl = 32; dl; dl >>= 1) m = fmaxf(m, __shfl_xor(m, dl));
  if ((tid & 63) == 0) red[tid >> 6] = m;
  __syncthreads();
  m = fmaxf(fmaxf(red[0], red[1]), fmaxf(red[2], red[3]));
  __syncthreads();
  float e = __expf(s - m);
  float sum = e;
  for (int dl = 32; dl; dl >>= 1) sum += __shfl_xor(sum, dl);
  if ((tid & 63) == 0) red[tid >> 6] = sum;
  __syncthreads();
  sum = red[0] + red[1] + red[2] + red[3];
  wl[tid] = e / sum;
  __syncthreads();
  float acc = 0.f;
  for (int t = 0; t < 256; ++t) acc += wl[t] * hl_f[(size_t)(b * 256 + t) * 256 + tid];
  rvec[tid] = acc;
  __syncthreads();
  if (tid < 128) {
    float a2 = 0.f;
    const float* wr = Wc2f + (size_t)tid * 256;
    for (int dk = 0; dk < 256; ++dk) a2 += rvec[dk] * wr[dk];
    rlcl[tid] = a2;
    vl[tid] = vcf[tid];
  }
  __syncthreads();
  const float* ap = Arc + (size_t)(b * 256 + tid) * 128;
  float s2 = 0.f;
  for (int k = 0; k < 128; ++k) s2 += vl[k] * (ap[k] + rlcl[k]);
  m = s2;
  for (int dl = 32; dl; dl >>= 1) m = fmaxf(m, __shfl_xor(m, dl));
  if ((tid & 63) == 0) red[tid >> 6] = m;
  __syncthreads();
  m = fmaxf(fmaxf(red[0], red[1]), fmaxf(red[2], red[3]));
  __syncthreads();
  float e2 = __expf(s2 - m);
  float sum2 = e2;
  for (int dl = 32; dl; dl >>= 1) sum2 += __shfl_xor(sum2, dl);
  if ((tid & 63) == 0) red[tid >> 6] = sum2;
  __syncthreads();
  sum2 = red[0] + red[1] + red[2] + red[3];
  wl[tid] = e2 / sum2;
  __syncthreads();
  float acc2 = 0.f;
  for (int t = 0; t < 256; ++t) acc2 += wl[t] * ar_f[(size_t)(b * 256 + t) * 256 + tid];
  rvec[tid] = acc2;
  __syncthreads();
  if (tid < 2) {
    float o = 0.f;
    const float* wp = Wpredf + (size_t)tid * 256;
    for (int dk = 0; dk < 256; ++dk) o += rvec[dk] * wp[dk];
    out[b * 2 + tid] = sigm(o);
  }
}

// ---------------- host ----------------

extern "C" void kernel_launch(void* const* d_in, const int* in_sizes, int n_in,
                              void* d_out, int out_size, void* d_ws, size_t ws_size,
                              hipStream_t stream) {
  (void)in_sizes; (void)n_in; (void)out_size; (void)ws_size;
  const int* inputs = (const int*)d_in[0];
  const float* embed = (const float*)d_in[1];
  const float* lWih = (const float*)d_in[2];
  const float* lWhh = (const float*)d_in[3];
  const float* lbih = (const float*)d_in[4];
  const float* lbhh = (const float*)d_in[5];
  const float* rWih = (const float*)d_in[6];
  const float* rWhh = (const float*)d_in[7];
  const float* rbih = (const float*)d_in[8];
  const float* rbhh = (const float*)d_in[9];
  const float* aWih = (const float*)d_in[10];
  const float* aWhh = (const float*)d_in[11];
  const float* abih = (const float*)d_in[12];
  const float* abhh = (const float*)d_in[13];
  const float* Wc1 = (const float*)d_in[14];
  const float* Wc2 = (const float*)d_in[15];
  const float* vc  = (const float*)d_in[16];
  const float* Wb  = (const float*)d_in[17];
  const float* Wd  = (const float*)d_in[18];
  const float* vd  = (const float*)d_in[19];
  const float* Wm  = (const float*)d_in[20];
  const float* vmv = (const float*)d_in[21];
  const float* Wsw = (const float*)d_in[22];
  const float* vsv = (const float*)d_in[23];
  const float* Wp  = (const float*)d_in[24];
  const float* vp  = (const float*)d_in[25];
  const float* Wpred = (const float*)d_in[26];

  char* ws = (char*)d_ws;
  size_t off = 0;
  auto alloc = [&](size_t bytes) -> void* {
    void* p = ws + off;
    off += (bytes + 255) & ~(size_t)255;
    return p;
  };
  unsigned short* xhi = (unsigned short*)alloc((size_t)M * EP * 2);
  unsigned short* xlo = (unsigned short*)alloc((size_t)M * EP * 2);
  unsigned short* wpad = (unsigned short*)alloc((size_t)4 * H3 * EP * 2);
  unsigned short* Whh_b = (unsigned short*)alloc((size_t)6 * H3 * H * 2);
  unsigned short* aWih_b = (unsigned short*)alloc((size_t)2 * H3 * H12 * 2);
  unsigned short* Wc1_b = (unsigned short*)alloc((size_t)H * H2 * 2);
  unsigned short* Wc2_b = (unsigned short*)alloc((size_t)H * H2 * 2);
  unsigned short* Wm_b  = (unsigned short*)alloc((size_t)H * H2 * 2);
  unsigned short* Wp_b  = (unsigned short*)alloc((size_t)H * H2 * 2);
  unsigned short* Wb_b  = (unsigned short*)alloc((size_t)H2 * H2 * 2);
  char* region1 = (char*)alloc((size_t)4 * M * H3 * 4);
  float* pre_lr = (float*)region1;
  float* S      = (float*)region1;
  float* pre_a  = (float*)region1;
  float* hl_f = (float*)alloc((size_t)M * H2 * 4);
  float* hr_f = (float*)alloc((size_t)M * H2 * 4);
  unsigned short* hl_hi = (unsigned short*)alloc((size_t)M * H2 * 2);
  unsigned short* hl_lo = (unsigned short*)alloc((size_t)M * H2 * 2);
  unsigned short* hr_hi = (unsigned short*)alloc((size_t)M * H2 * 2);
  unsigned short* hr_lo = (unsigned short*)alloc((size_t)M * H2 * 2);
  float* Hc = (float*)alloc((size_t)M * H * 4);
  float* Rc = (float*)alloc((size_t)M * H * 4);
  float* Hm = (float*)alloc((size_t)M * H * 4);
  float* Rm = (float*)alloc((size_t)M * H * 4);
  float* Hp = (float*)alloc((size_t)M * H * 4);
  float* HB = (float*)alloc((size_t)M * H2 * 4);
  unsigned short* agg_hi = (unsigned short*)alloc((size_t)M * H12 * 2);
  unsigned short* agg_lo = (unsigned short*)alloc((size_t)M * H12 * 2);
  float* ar_f = (float*)alloc((size_t)M * H2 * 4);
  unsigned short* ar_hi = (unsigned short*)alloc((size_t)M * H2 * 2);
  unsigned short* ar_lo = (unsigned short*)alloc((size_t)M * H2 * 2);
  float* Arc = (float*)alloc((size_t)M * H * 4);

  // 1. staging
  StageArgs sa{};
  sa.cs[0] = lWhh;  sa.cd[0] = Whh_b;                 sa.cn[0] = 2 * H3 * H;
  sa.cs[1] = rWhh;  sa.cd[1] = Whh_b + 2 * H3 * H;    sa.cn[1] = 2 * H3 * H;
  sa.cs[2] = aWhh;  sa.cd[2] = Whh_b + 4 * H3 * H;    sa.cn[2] = 2 * H3 * H;
  sa.cs[3] = aWih;  sa.cd[3] = aWih_b;                sa.cn[3] = 2 * H3 * H12;
  sa.cs[4] = Wc1;   sa.cd[4] = Wc1_b;                 sa.cn[4] = H * H2;
  sa.cs[5] = Wc2;   sa.cd[5] = Wc2_b;                 sa.cn[5] = H * H2;
  sa.cs[6] = Wm;    sa.cd[6] = Wm_b;                  sa.cn[6] = H * H2;
  sa.cs[7] = Wp;    sa.cd[7] = Wp_b;                  sa.cn[7] = H * H2;
  sa.cs[8] = Wb;    sa.cd[8] = Wb_b;                  sa.cn[8] = H2 * H2;
  sa.idx = inputs; sa.emb = embed; sa.xhi = xhi; sa.xlo = xlo;
  sa.lW = lWih; sa.rW = rWih; sa.wpad = wpad;
  k_stage<<<dim3((2 * H3 * H12 + 255) / 256, 11), dim3(256), 0, stream>>>(sa);

  // 2. input projections for l/r GRUs
  GemmBatch ga{};
  const float* biases[4] = { lbih, lbih + H3, rbih, rbih + H3 };
  for (int u = 0; u < 4; ++u)
    ga.d[u] = GemmDesc{ xhi, xlo, wpad + (size_t)u * H3 * EP, biases[u],
                        pre_lr + (size_t)u * M * H3, H3, EP };
  k_gemm<<<dim3(16, 6, 4), dim3(256), 0, stream>>>(ga);

  // 3. l/r recurrences (writes fp32 + hi/lo + agg hr-copy)
  RecArgs r1{};
  r1.whh[0] = Whh_b;               r1.whh[1] = Whh_b + H3 * H;
  r1.whh[2] = Whh_b + 2 * H3 * H;  r1.whh[3] = Whh_b + 3 * H3 * H;
  for (int u = 0; u < 4; ++u) r1.pre[u] = pre_lr + (size_t)u * M * H3;
  r1.outf[0] = r1.outf[1] = hl_f; r1.outf[2] = r1.outf[3] = hr_f;
  r1.outhi[0] = r1.outhi[1] = hl_hi; r1.outhi[2] = r1.outhi[3] = hr_hi;
  r1.outlo[0] = r1.outlo[1] = hl_lo; r1.outlo[2] = r1.outlo[3] = hr_lo;
  r1.agghi[0] = r1.agghi[1] = nullptr; r1.agghi[2] = r1.agghi[3] = agg_hi;
  r1.agglo[0] = r1.agglo[1] = nullptr; r1.agglo[2] = r1.agglo[3] = agg_lo;
  r1.bhh[0] = lbhh; r1.bhh[1] = lbhh + H3; r1.bhh[2] = rbhh; r1.bhh[3] = rbhh + H3;
  r1.colOff[0] = 0; r1.colOff[1] = H; r1.colOff[2] = 0; r1.colOff[3] = H;
  r1.dir[0] = 0; r1.dir[1] = 1; r1.dir[2] = 0; r1.dir[3] = 1;
  k_gru<<<dim3(4), dim3(512), 0, stream>>>(r1);

  // 4. projection GEMMs
  GemmBatch gbB{};
  gbB.d[0] = GemmDesc{ hl_hi, hl_lo, Wc1_b, nullptr, Hc, H, H2 };
  gbB.d[1] = GemmDesc{ hr_hi, hr_lo, Wc2_b, nullptr, Rc, H, H2 };
  gbB.d[2] = GemmDesc{ hl_hi, hl_lo, Wm_b, nullptr, Hm, H, H2 };
  gbB.d[3] = GemmDesc{ hr_hi, hr_lo, Wm_b, nullptr, Rm, H, H2 };
  gbB.d[4] = GemmDesc{ hl_hi, hl_lo, Wb_b, nullptr, HB, H2, H2 };
  gbB.d[5] = GemmDesc{ hl_hi, hl_lo, Wp_b, nullptr, Hp, H, H2 };
  k_gemm<<<dim3(16, 4, 6), dim3(256), 0, stream>>>(gbB);

  // 5. all scores (one dispatch)
  ScArgs sc{};
  sc.Xhi[0] = hl_hi; sc.Wt[0] = Wd;  sc.vt[0] = vd;  sc.So[0] = S + (size_t)2 * STY;
  sc.Xhi[1] = hr_hi; sc.Wt[1] = Wsw; sc.vt[1] = vsv; sc.So[1] = S + (size_t)0 * STY;
  sc.Rf = hr_f;
  sc.Hc = Hc; sc.Rc = Rc; sc.Hm = Hm; sc.Rm = Rm; sc.HB = HB;
  sc.hrf = hr_f; sc.vcf = vc; sc.vmf = vmv; sc.S = S;
  k_score<<<dim3(M, 3), dim3(256), 0, stream>>>(sc);

  // 6. softmax + weighted sums into agg
  k_wsum<<<dim3(32, 5, 4), dim3(256), 0, stream>>>(S, hl_f, hr_f, agg_hi, agg_lo);

  // 7. agg GRU input projection
  GemmBatch gc{};
  gc.d[0] = GemmDesc{ agg_hi, agg_lo, aWih_b, abih, pre_a, H3, H12 };
  gc.d[1] = GemmDesc{ agg_hi, agg_lo, aWih_b + (size_t)H3 * H12, abih + H3,
                      pre_a + (size_t)M * H3, H3, H12 };
  k_gemm<<<dim3(16, 6, 2), dim3(256), 0, stream>>>(gc);

  // 8. agg recurrence (writes ar fp32 + hi/lo)
  RecArgs r2{};
  r2.whh[0] = Whh_b + 4 * H3 * H; r2.whh[1] = Whh_b + 5 * H3 * H;
  r2.whh[2] = r2.whh[3] = Whh_b + 4 * H3 * H;
  r2.pre[0] = pre_a; r2.pre[1] = pre_a + (size_t)M * H3;
  r2.pre[2] = r2.pre[3] = pre_a;
  r2.outf[0] = r2.outf[1] = r2.outf[2] = r2.outf[3] = ar_f;
  r2.outhi[0] = r2.outhi[1] = r2.outhi[2] = r2.outhi[3] = ar_hi;
  r2.outlo[0] = r2.outlo[1] = r2.outlo[2] = r2.outlo[3] = ar_lo;
  for (int u = 0; u < 4; ++u) { r2.agghi[u] = nullptr; r2.agglo[u] = nullptr; }
  r2.bhh[0] = abhh; r2.bhh[1] = abhh + H3; r2.bhh[2] = r2.bhh[3] = abhh;
  r2.colOff[0] = 0; r2.colOff[1] = H; r2.colOff[2] = r2.colOff[3] = 0;
  r2.dir[0] = 0; r2.dir[1] = 1; r2.dir[2] = r2.dir[3] = 0;
  k_gru<<<dim3(2), dim3(512), 0, stream>>>(r2);

  // 9. Arc GEMM
  GemmBatch gd{};
  gd.d[0] = GemmDesc{ ar_hi, ar_lo, Wc1_b, nullptr, Arc, H, H2 };
  k_gemm<<<dim3(16, 2, 1), dim3(256), 0, stream>>>(gd);

  // 10. fused tail
  k_tail<<<dim3(4), dim3(256), 0, stream>>>(Hp, hl_f, vp, Wc2, Arc, ar_f, vc, Wpred,
                                            (float*)d_out);
}